// Round 6
// baseline (1563.720 us; speedup 1.0000x reference)
//
#include <hip/hip_runtime.h>
#include <hip/hip_bf16.h>

#define D 768
#define NQ 64
#define TPB 256
#define GRID 1024
#define NPAIR (GRID * 2)      // candidate lists per query (block × row-half)
#define KSTEPS 24             // 768 / 32
#define SCST 17               // padded floats per query row in transpose scratch
#define NS 8                  // merge1 segments per query

typedef float    f32x4 __attribute__((ext_vector_type(4)));
typedef _Float16 h16x8 __attribute__((ext_vector_type(8)));

// ---------- top-k helpers (static-indexed: stays in VGPRs) ----------
__device__ __forceinline__ bool kbetter(float v1, int i1, float v2, int i2) {
    return (v1 > v2) || (v1 == v2 && i1 < i2);
}

__device__ __forceinline__ void topk_insert(float (&tv)[16], int (&ti)[16], float v, int idx) {
    if (!kbetter(v, idx, tv[15], ti[15])) return;
    tv[15] = v; ti[15] = idx;
    #pragma unroll
    for (int s = 15; s >= 1; --s) {
        bool sw = kbetter(tv[s], ti[s], tv[s-1], ti[s-1]);
        float av = sw ? tv[s] : tv[s-1];
        float bv = sw ? tv[s-1] : tv[s];
        int   ai = sw ? ti[s] : ti[s-1];
        int   bi = sw ? ti[s-1] : ti[s];
        tv[s-1] = av; tv[s] = bv; ti[s-1] = ai; ti[s] = bi;
    }
}

__device__ __forceinline__ void bitonic16(float (&v)[16], int (&ix)[16]) {
    #pragma unroll
    for (int d = 8; d >= 1; d >>= 1) {
        #pragma unroll
        for (int i = 0; i < 16; ++i) {
            if ((i & d) == 0) {
                int j = i | d;
                bool sw = kbetter(v[j], ix[j], v[i], ix[i]);
                float av = sw ? v[j] : v[i];
                float bv = sw ? v[i] : v[j];
                int   ai = sw ? ix[j] : ix[i];
                int   bi = sw ? ix[i] : ix[j];
                v[i] = av; v[j] = bv; ix[i] = ai; ix[j] = bi;
            }
        }
    }
}

__device__ __forceinline__ void lane_merge(float (&v)[16], int (&ix)[16], int mask) {
    float pv[16]; int pix[16];
    #pragma unroll
    for (int i = 0; i < 16; ++i) {
        pv[i]  = __shfl_xor(v[15 - i], mask);
        pix[i] = __shfl_xor(ix[15 - i], mask);
    }
    #pragma unroll
    for (int i = 0; i < 16; ++i) {
        if (kbetter(pv[i], pix[i], v[i], ix[i])) { v[i] = pv[i]; ix[i] = pix[i]; }
    }
    bitonic16(v, ix);
}

__device__ __forceinline__ void sort64(float& v, int& ix, int l) {
    #pragma unroll
    for (int k = 2; k <= 64; k <<= 1) {
        #pragma unroll
        for (int j = k >> 1; j >= 1; j >>= 1) {
            float ov = __shfl_xor(v, j);
            int   oi = __shfl_xor(ix, j);
            bool dirDesc = ((l & k) == 0);
            bool lower   = ((l & j) == 0);
            bool takeBetter = (lower == dirDesc);
            bool ob = kbetter(ov, oi, v, ix);
            if (takeBetter == ob) { v = ov; ix = oi; }
        }
    }
}

// ---------- kernel 0: normalize Q rows, fp16 hi/lo split, packed fragment order ----------
// layout: [ks(24)][qf(4)][lane(64)][hi 8 | lo 8] halves  (32 B per lane-fragment)
__global__ __launch_bounds__(256)
void prep_kernel(const float* __restrict__ query, _Float16* __restrict__ qpk) {
    int b = blockIdx.x, t = threadIdx.x;
    const float* row = query + b * D;
    float vals[3]; float s = 0.f;
    #pragma unroll
    for (int j = 0; j < 3; ++j) { vals[j] = row[t + 256 * j]; s += vals[j] * vals[j]; }
    #pragma unroll
    for (int m = 1; m < 64; m <<= 1) s += __shfl_xor(s, m);
    __shared__ float ws4[4];
    if ((t & 63) == 0) ws4[t >> 6] = s;
    __syncthreads();
    float qn = sqrtf(ws4[0] + ws4[1] + ws4[2] + ws4[3]);
    int qf = b >> 4;
    #pragma unroll
    for (int j = 0; j < 3; ++j) {
        int col = t + 256 * j;
        float vn = vals[j] / qn;
        _Float16 h = (_Float16)vn;
        float r = vn - (float)h;
        _Float16 l2 = (_Float16)(r * 2048.0f);
        int ks = col >> 5, unit = (col >> 3) & 3, sub = col & 7;
        int lane = (b & 15) + unit * 16;
        size_t off = (((size_t)ks * 4 + qf) * 64 + lane) * 16 + sub;
        qpk[off]     = h;
        qpk[off + 8] = l2;
    }
}

// ---------- kernel 1: barrier-free, query-split wave pairs, deep reg prefetch ----------
// Block = 4 waves. Wave w: row-half h=(w>>1) (16 rows), query-half (w&1) (32 queries).
// Wave pair (h fixed) reads identical corpus rows -> L1/MSHR merge, no extra HBM.
// Lane l owns query (w&1)*32 + (l&31)'s running top-16.

#define QLOADM(ks, qh0, ql0, qh1, ql1) do {                                    \
    const _Float16* qp0 = qpk + (((size_t)(ks) * 4 + qb) * 64 + l) * 16;       \
    qh0 = *(const h16x8*)qp0;  ql0 = *(const h16x8*)(qp0 + 8);                 \
    const _Float16* qp1 = qp0 + 64 * 16;                                       \
    qh1 = *(const h16x8*)qp1;  ql1 = *(const h16x8*)(qp1 + 8);                 \
  } while (0)

#define CLOADM(ks, c0, c1) do {                                                \
    c0 = *(const f32x4*)(pc + (ks) * 32);                                      \
    c1 = *(const f32x4*)(pc + (ks) * 32 + 4);                                  \
  } while (0)

#define STEPM(ks, c0, c1, qh0, ql0, qh1, ql1, n0, n1, nqh0, nql0, nqh1, nql1)  \
  do {                                                                         \
    if ((ks) + 1 < KSTEPS) {                                                   \
        CLOADM((ks) + 1, n0, n1);                                              \
        QLOADM((ks) + 1, nqh0, nql0, nqh1, nql1);                              \
    }                                                                          \
    h16x8 hi, lo;                                                              \
    _Pragma("unroll")                                                          \
    for (int i = 0; i < 4; ++i) {                                              \
        float v0 = c0[i]; _Float16 h0 = (_Float16)v0;                          \
        hi[i] = h0; lo[i] = (_Float16)((v0 - (float)h0) * 2048.0f);            \
        ps += v0 * v0;                                                         \
        float v1 = c1[i]; _Float16 h1 = (_Float16)v1;                          \
        hi[4 + i] = h1; lo[4 + i] = (_Float16)((v1 - (float)h1) * 2048.0f);    \
        ps += v1 * v1;                                                         \
    }                                                                          \
    aH0 = __builtin_amdgcn_mfma_f32_16x16x32_f16(qh0, hi, aH0, 0, 0, 0);       \
    aX0 = __builtin_amdgcn_mfma_f32_16x16x32_f16(qh0, lo, aX0, 0, 0, 0);       \
    aX0 = __builtin_amdgcn_mfma_f32_16x16x32_f16(ql0, hi, aX0, 0, 0, 0);       \
    aH1 = __builtin_amdgcn_mfma_f32_16x16x32_f16(qh1, hi, aH1, 0, 0, 0);       \
    aX1 = __builtin_amdgcn_mfma_f32_16x16x32_f16(qh1, lo, aX1, 0, 0, 0);       \
    aX1 = __builtin_amdgcn_mfma_f32_16x16x32_f16(ql1, hi, aX1, 0, 0, 0);       \
  } while (0)

__global__ __launch_bounds__(TPB, 4)
void sim_topk_kernel(const float* __restrict__ corpus,
                     const _Float16* __restrict__ qpk,
                     float2* __restrict__ cand,   // [NQ][NPAIR][16]
                     int N, int NG) {
    __shared__ float scratch[4][32 * SCST];   // per-wave private transpose tile
    int t = threadIdx.x, w = t >> 6, l = t & 63;
    int h  = w >> 1;          // row-half within group
    int qb = (w & 1) * 2;     // q-fragment base (2 frags = 32 queries)
    int n16 = l & 15, kg = l >> 4;
    float* sc = scratch[w];

    float tv[16]; int ti[16];
    #pragma unroll
    for (int s = 0; s < 16; ++s) { tv[s] = -INFINITY; ti[s] = 0x7fffffff; }

    for (int g = blockIdx.x; g < NG; g += GRID) {
        long rowg = (long)g * 32 + h * 16 + n16;
        if (rowg > N - 1) rowg = N - 1;
        const float* pc = corpus + (size_t)rowg * D + kg * 8;

        f32x4 aH0 = (f32x4)(0.f), aX0 = (f32x4)(0.f);
        f32x4 aH1 = (f32x4)(0.f), aX1 = (f32x4)(0.f);
        float ps = 0.f;

        f32x4 cA0, cA1, cB0, cB1;
        h16x8 qhA0, qlA0, qhA1, qlA1, qhB0, qlB0, qhB1, qlB1;
        CLOADM(0, cA0, cA1);
        QLOADM(0, qhA0, qlA0, qhA1, qlA1);

        #pragma unroll
        for (int m = 0; m < KSTEPS / 2; ++m) {
            STEPM(2 * m,     cA0, cA1, qhA0, qlA0, qhA1, qlA1,
                             cB0, cB1, qhB0, qlB0, qhB1, qlB1);
            STEPM(2 * m + 1, cB0, cB1, qhB0, qlB0, qhB1, qlB1,
                             cA0, cA1, qhA0, qlA0, qhA1, qlA1);
        }

        // corpus row norm: lanes {l, l^16, l^32, l^48} hold k-slices of row (l&15)
        ps += __shfl_xor(ps, 16);
        ps += __shfl_xor(ps, 32);
        float inv = 1.0f / sqrtf(ps);

        // per-wave transpose: write (qloc, n) -> scratch, read per-query rows
        #pragma unroll
        for (int qf = 0; qf < 2; ++qf)
            #pragma unroll
            for (int r = 0; r < 4; ++r) {
                int qloc = qf * 16 + kg * 4 + r;
                float dH = qf ? aH1[r] : aH0[r];
                float dX = qf ? aX1[r] : aX0[r];
                sc[qloc * SCST + n16] = (dH + dX * (1.0f / 2048.0f)) * inv;
            }
        {
            int qloc = l & 31, nh = (l >> 5) * 8;
            f32x4 s0 = *(const f32x4*)(sc + qloc * SCST + nh);
            f32x4 s1 = *(const f32x4*)(sc + qloc * SCST + nh + 4);
            long gbase = (long)g * 32 + h * 16 + nh;
            #pragma unroll
            for (int e = 0; e < 4; ++e) {
                long gi = gbase + e;
                if (gi < N) topk_insert(tv, ti, s0[e], (int)gi);
            }
            #pragma unroll
            for (int e = 0; e < 4; ++e) {
                long gi = gbase + 4 + e;
                if (gi < N) topk_insert(tv, ti, s1[e], (int)gi);
            }
        }
    }

    // lanes l and l+32 hold the two n-halves of query qb*16 + (l&31): merge, write
    lane_merge(tv, ti, 32);
    if (l < 32) {
        int q = (w & 1) * 32 + l;
        int pair = blockIdx.x * 2 + h;
        float2* dst = cand + ((size_t)q * NPAIR + pair) * 16;
        #pragma unroll
        for (int s = 0; s < 16; ++s) dst[s] = make_float2(tv[s], __int_as_float(ti[s]));
    }
}

// ---------- kernel 2a: partial merge — 8 segments per query ----------
__global__ __launch_bounds__(256)
void merge1_kernel(const float2* __restrict__ cand, float2* __restrict__ cand2, int NWV) {
    int q = blockIdx.x >> 3, seg = blockIdx.x & (NS - 1);
    int t = threadIdx.x, w = t >> 6, l = t & 63;
    int total = NWV * 16;
    int chunk = (total + NS - 1) / NS;
    int e0 = seg * chunk, e1 = min(total, e0 + chunk);
    const float2* src = cand + (size_t)q * total;
    float tv[16]; int ti[16];
    #pragma unroll
    for (int s = 0; s < 16; ++s) { tv[s] = -INFINITY; ti[s] = 0x7fffffff; }
    for (int e = e0 + t; e < e1; e += 256) {
        float2 ce = src[e];
        topk_insert(tv, ti, ce.x, __float_as_int(ce.y));
    }
    lane_merge(tv, ti, 1);  lane_merge(tv, ti, 2);  lane_merge(tv, ti, 4);
    lane_merge(tv, ti, 8);  lane_merge(tv, ti, 16); lane_merge(tv, ti, 32);
    __shared__ float2 stage[64];
    if (l == 0) {
        #pragma unroll
        for (int s = 0; s < 16; ++s) stage[w * 16 + s] = make_float2(tv[s], __int_as_float(ti[s]));
    }
    __syncthreads();
    if (t < 64) {
        float2 ce = stage[t];
        float v = ce.x; int ix = __float_as_int(ce.y);
        sort64(v, ix, t);
        if (t < 16) cand2[((size_t)q * NS + seg) * 16 + t] = make_float2(v, __int_as_float(ix));
    }
}

// ---------- kernel 2b: final merge of 8x16=128 candidates per query ----------
__global__ __launch_bounds__(64)
void merge2_kernel(const float2* __restrict__ cand2, float* __restrict__ out) {
    int q = blockIdx.x, l = threadIdx.x;
    const float2* src = cand2 + (size_t)q * (NS * 16);
    float2 a = src[l], b = src[l + 64];
    float v1 = a.x; int i1 = __float_as_int(a.y);
    float v2 = b.x; int i2 = __float_as_int(b.y);
    sort64(v1, i1, l);
    sort64(v2, i2, l);
    float sv = __shfl(v2, (l - 16) & 63);
    int   si = __shfl(i2, (l - 16) & 63);
    float mv = (l < 16) ? v1 : ((l < 32) ? sv : -INFINITY);
    int   mi = (l < 16) ? i1 : ((l < 32) ? si : 0x7fffffff);
    sort64(mv, mi, l);
    if (l < 16) {
        out[q * 16 + l]           = mv;
        out[NQ * 16 + q * 16 + l] = (float)mi;
    }
}

extern "C" void kernel_launch(void* const* d_in, const int* in_sizes, int n_in,
                              void* d_out, int out_size, void* d_ws, size_t ws_size,
                              hipStream_t stream) {
    const float* query  = (const float*)d_in[0];
    const float* corpus = (const float*)d_in[1];
    int N  = in_sizes[1] / D;                 // 500000
    int NG = (N + 31) / 32;                   // 15625 row-groups of 32
    char* ws = (char*)d_ws;
    _Float16* qpk = (_Float16*)ws;                              // 196608 B
    float2*  cand = (float2*)(ws + 196608);                     // 64*NPAIR*16*8 B (16 MB)
    size_t candBytes = (size_t)NQ * NPAIR * 16 * sizeof(float2);
    float2* cand2 = (float2*)(ws + 196608 + candBytes);         // 64KB
    float*   out  = (float*)d_out;

    prep_kernel<<<NQ, 256, 0, stream>>>(query, qpk);
    sim_topk_kernel<<<GRID, TPB, 0, stream>>>(corpus, qpk, cand, N, NG);
    merge1_kernel<<<NQ * NS, 256, 0, stream>>>(cand, cand2, NPAIR);
    merge2_kernel<<<NQ, 64, 0, stream>>>(cand2, out);
}

// Round 7
// 907.086 us; speedup vs baseline: 1.7239x; 1.7239x over previous
//
#include <hip/hip_runtime.h>
#include <hip/hip_bf16.h>

#define D 768
#define NQ 64
#define TPB 256
#define GRID 1024
#define NWT (GRID * 4)        // sim waves = 4096
#define KSTEPS 24             // 768 / 32
#define SCST 17               // padded floats per q-row in transpose scratch
#define NMW 4096              // mergeA candidate lists per query
#define NS 8                  // merge1 segments per query

typedef float    f32x4 __attribute__((ext_vector_type(4)));
typedef _Float16 h16x8 __attribute__((ext_vector_type(8)));

// ---------- top-k helpers (static-indexed: stays in VGPRs) ----------
__device__ __forceinline__ bool kbetter(float v1, int i1, float v2, int i2) {
    return (v1 > v2) || (v1 == v2 && i1 < i2);
}

__device__ __forceinline__ void topk_insert(float (&tv)[16], int (&ti)[16], float v, int idx) {
    if (!kbetter(v, idx, tv[15], ti[15])) return;
    tv[15] = v; ti[15] = idx;
    #pragma unroll
    for (int s = 15; s >= 1; --s) {
        bool sw = kbetter(tv[s], ti[s], tv[s-1], ti[s-1]);
        float av = sw ? tv[s] : tv[s-1];
        float bv = sw ? tv[s-1] : tv[s];
        int   ai = sw ? ti[s] : ti[s-1];
        int   bi = sw ? ti[s-1] : ti[s];
        tv[s-1] = av; tv[s] = bv; ti[s-1] = ai; ti[s] = bi;
    }
}

__device__ __forceinline__ void bitonic16(float (&v)[16], int (&ix)[16]) {
    #pragma unroll
    for (int d = 8; d >= 1; d >>= 1) {
        #pragma unroll
        for (int i = 0; i < 16; ++i) {
            if ((i & d) == 0) {
                int j = i | d;
                bool sw = kbetter(v[j], ix[j], v[i], ix[i]);
                float av = sw ? v[j] : v[i];
                float bv = sw ? v[i] : v[j];
                int   ai = sw ? ix[j] : ix[i];
                int   bi = sw ? ix[i] : ix[j];
                v[i] = av; v[j] = bv; ix[i] = ai; ix[j] = bi;
            }
        }
    }
}

__device__ __forceinline__ void lane_merge(float (&v)[16], int (&ix)[16], int mask) {
    float pv[16]; int pix[16];
    #pragma unroll
    for (int i = 0; i < 16; ++i) {
        pv[i]  = __shfl_xor(v[15 - i], mask);
        pix[i] = __shfl_xor(ix[15 - i], mask);
    }
    #pragma unroll
    for (int i = 0; i < 16; ++i) {
        if (kbetter(pv[i], pix[i], v[i], ix[i])) { v[i] = pv[i]; ix[i] = pix[i]; }
    }
    bitonic16(v, ix);
}

__device__ __forceinline__ void sort64(float& v, int& ix, int l) {
    #pragma unroll
    for (int k = 2; k <= 64; k <<= 1) {
        #pragma unroll
        for (int j = k >> 1; j >= 1; j >>= 1) {
            float ov = __shfl_xor(v, j);
            int   oi = __shfl_xor(ix, j);
            bool dirDesc = ((l & k) == 0);
            bool lower   = ((l & j) == 0);
            bool takeBetter = (lower == dirDesc);
            bool ob = kbetter(ov, oi, v, ix);
            if (takeBetter == ob) { v = ov; ix = oi; }
        }
    }
}

// ---------- kernel 0: normalize Q rows, fp16 hi/lo split, packed fragment order ----------
// layout: [ks(24)][qf(4)][lane(64)][hi 8 | lo 8] halves  (32 B per lane-fragment)
__global__ __launch_bounds__(256)
void prep_kernel(const float* __restrict__ query, _Float16* __restrict__ qpk) {
    int b = blockIdx.x, t = threadIdx.x;
    const float* row = query + b * D;
    float vals[3]; float s = 0.f;
    #pragma unroll
    for (int j = 0; j < 3; ++j) { vals[j] = row[t + 256 * j]; s += vals[j] * vals[j]; }
    #pragma unroll
    for (int m = 1; m < 64; m <<= 1) s += __shfl_xor(s, m);
    __shared__ float ws4[4];
    if ((t & 63) == 0) ws4[t >> 6] = s;
    __syncthreads();
    float qn = sqrtf(ws4[0] + ws4[1] + ws4[2] + ws4[3]);
    int qf = b >> 4;
    #pragma unroll
    for (int j = 0; j < 3; ++j) {
        int col = t + 256 * j;
        float vn = vals[j] / qn;
        _Float16 h = (_Float16)vn;
        float r = vn - (float)h;
        _Float16 l2 = (_Float16)(r * 2048.0f);
        int ks = col >> 5, unit = (col >> 3) & 3, sub = col & 7;
        int lane = (b & 15) + unit * 16;
        size_t off = (((size_t)ks * 4 + qf) * 64 + lane) * 16 + sub;
        qpk[off]     = h;
        qpk[off + 8] = l2;
    }
}

// ---------- kernel 1: pure streaming sim — no topk state, no spills ----------
// Wave-independent: each wave owns 16 corpus rows per group, all 64 queries.
// Writes sim[n][q] (coalesced 256B rows) via per-wave LDS transpose.
__global__ __launch_bounds__(TPB, 4)
void sim_kernel(const float* __restrict__ corpus,
                const _Float16* __restrict__ qpk,
                float* __restrict__ simout, int N, int NG16) {
    __shared__ float scratch[4][NQ * SCST];
    int t = threadIdx.x, w = t >> 6, l = t & 63;
    int ww = blockIdx.x * 4 + w;
    int n16 = l & 15, kg = l >> 4;
    float* sc = scratch[w];

    for (int g = ww; g < NG16; g += NWT) {
        long rowg = (long)g * 16 + n16;
        if (rowg > N - 1) rowg = N - 1;
        const float* pc = corpus + (size_t)rowg * D + kg * 8;

        f32x4 accH[4], accX[4];
        #pragma unroll
        for (int qf = 0; qf < 4; ++qf) { accH[qf] = (f32x4)(0.f); accX[qf] = (f32x4)(0.f); }
        float ps = 0.f;

        #pragma unroll 2
        for (int ks = 0; ks < KSTEPS; ++ks) {
            f32x4 c0 = __builtin_nontemporal_load((const f32x4*)(pc + ks * 32));
            f32x4 c1 = __builtin_nontemporal_load((const f32x4*)(pc + ks * 32 + 4));
            h16x8 hi, lo;
            #pragma unroll
            for (int i = 0; i < 4; ++i) {
                float v0 = c0[i]; _Float16 h0 = (_Float16)v0;
                hi[i] = h0; lo[i] = (_Float16)((v0 - (float)h0) * 2048.0f);
                ps += v0 * v0;
                float v1 = c1[i]; _Float16 h1 = (_Float16)v1;
                hi[4 + i] = h1; lo[4 + i] = (_Float16)((v1 - (float)h1) * 2048.0f);
                ps += v1 * v1;
            }
            #pragma unroll
            for (int qf = 0; qf < 4; ++qf) {
                const _Float16* qp = qpk + (((size_t)ks * 4 + qf) * 64 + l) * 16;
                h16x8 qh = *(const h16x8*)qp;
                h16x8 ql = *(const h16x8*)(qp + 8);
                accH[qf] = __builtin_amdgcn_mfma_f32_16x16x32_f16(qh, hi, accH[qf], 0, 0, 0);
                accX[qf] = __builtin_amdgcn_mfma_f32_16x16x32_f16(qh, lo, accX[qf], 0, 0, 0);
                accX[qf] = __builtin_amdgcn_mfma_f32_16x16x32_f16(ql, hi, accX[qf], 0, 0, 0);
            }
        }

        // corpus row norm: lanes {l, l^16, l^32, l^48} hold k-slices of row n16
        ps += __shfl_xor(ps, 16);
        ps += __shfl_xor(ps, 32);
        float inv = 1.0f / sqrtf(ps);

        // per-wave transpose (wave-private tile; lgkmcnt orders, no barrier)
        #pragma unroll
        for (int qf = 0; qf < 4; ++qf)
            #pragma unroll
            for (int r = 0; r < 4; ++r) {
                int q = qf * 16 + kg * 4 + r;
                sc[q * SCST + n16] = (accH[qf][r] + accX[qf][r] * (1.0f / 2048.0f)) * inv;
            }
        f32x4 sv[4];
        #pragma unroll
        for (int j4 = 0; j4 < 4; ++j4) sv[j4] = *(const f32x4*)(sc + l * SCST + j4 * 4);
        // lane l holds query l's sims for rows g*16..g*16+15 -> coalesced [n][q] stores
        float* so = simout + (size_t)g * 16 * NQ + l;
        #pragma unroll
        for (int j4 = 0; j4 < 4; ++j4)
            #pragma unroll
            for (int e = 0; e < 4; ++e)
                __builtin_nontemporal_store(sv[j4][e], so + (size_t)(j4 * 4 + e) * NQ);
    }
}

// ---------- kernel 2: stream sims -> per-wave per-query top-16 ----------
// Lane l owns query l. Wave reads sim[n][0..63] = 256B coalesced per n.
__global__ __launch_bounds__(256)
void mergeA_kernel(const float* __restrict__ simout, float2* __restrict__ candA, int N) {
    int t = threadIdx.x, w = t >> 6, l = t & 63;
    int ww = blockIdx.x * 4 + w;              // 0..NMW-1
    int chunk = (N + NMW - 1) / NMW;
    int n0 = ww * chunk, n1 = min(N, n0 + chunk);

    float tv[16]; int ti[16];
    #pragma unroll
    for (int s = 0; s < 16; ++s) { tv[s] = -INFINITY; ti[s] = 0x7fffffff; }

    int n = n0;
    for (; n + 8 <= n1; n += 8) {
        float v[8];
        #pragma unroll
        for (int j = 0; j < 8; ++j)
            v[j] = __builtin_nontemporal_load(simout + (size_t)(n + j) * NQ + l);
        #pragma unroll
        for (int j = 0; j < 8; ++j) topk_insert(tv, ti, v[j], n + j);
    }
    for (; n < n1; ++n) {
        float v = __builtin_nontemporal_load(simout + (size_t)n * NQ + l);
        topk_insert(tv, ti, v, n);
    }

    float2* dst = candA + ((size_t)l * NMW + ww) * 16;
    #pragma unroll
    for (int s = 0; s < 16; ++s) dst[s] = make_float2(tv[s], __int_as_float(ti[s]));
}

// ---------- kernel 3: partial merge — 8 segments per query ----------
__global__ __launch_bounds__(256)
void merge1_kernel(const float2* __restrict__ cand, float2* __restrict__ cand2, int NWV) {
    int q = blockIdx.x >> 3, seg = blockIdx.x & (NS - 1);
    int t = threadIdx.x, w = t >> 6, l = t & 63;
    int total = NWV * 16;
    int chunk = (total + NS - 1) / NS;
    int e0 = seg * chunk, e1 = min(total, e0 + chunk);
    const float2* src = cand + (size_t)q * total;
    float tv[16]; int ti[16];
    #pragma unroll
    for (int s = 0; s < 16; ++s) { tv[s] = -INFINITY; ti[s] = 0x7fffffff; }
    for (int e = e0 + t; e < e1; e += 256) {
        float2 ce = src[e];
        topk_insert(tv, ti, ce.x, __float_as_int(ce.y));
    }
    lane_merge(tv, ti, 1);  lane_merge(tv, ti, 2);  lane_merge(tv, ti, 4);
    lane_merge(tv, ti, 8);  lane_merge(tv, ti, 16); lane_merge(tv, ti, 32);
    __shared__ float2 stage[64];
    if (l == 0) {
        #pragma unroll
        for (int s = 0; s < 16; ++s) stage[w * 16 + s] = make_float2(tv[s], __int_as_float(ti[s]));
    }
    __syncthreads();
    if (t < 64) {
        float2 ce = stage[t];
        float v = ce.x; int ix = __float_as_int(ce.y);
        sort64(v, ix, t);
        if (t < 16) cand2[((size_t)q * NS + seg) * 16 + t] = make_float2(v, __int_as_float(ix));
    }
}

// ---------- kernel 4: final merge of 8x16=128 candidates per query ----------
__global__ __launch_bounds__(64)
void merge2_kernel(const float2* __restrict__ cand2, float* __restrict__ out) {
    int q = blockIdx.x, l = threadIdx.x;
    const float2* src = cand2 + (size_t)q * (NS * 16);
    float2 a = src[l], b = src[l + 64];
    float v1 = a.x; int i1 = __float_as_int(a.y);
    float v2 = b.x; int i2 = __float_as_int(b.y);
    sort64(v1, i1, l);
    sort64(v2, i2, l);
    float sv = __shfl(v2, (l - 16) & 63);
    int   si = __shfl(i2, (l - 16) & 63);
    float mv = (l < 16) ? v1 : ((l < 32) ? sv : -INFINITY);
    int   mi = (l < 16) ? i1 : ((l < 32) ? si : 0x7fffffff);
    sort64(mv, mi, l);
    if (l < 16) {
        out[q * 16 + l]           = mv;
        out[NQ * 16 + q * 16 + l] = (float)mi;
    }
}

extern "C" void kernel_launch(void* const* d_in, const int* in_sizes, int n_in,
                              void* d_out, int out_size, void* d_ws, size_t ws_size,
                              hipStream_t stream) {
    const float* query  = (const float*)d_in[0];
    const float* corpus = (const float*)d_in[1];
    int N    = in_sizes[1] / D;               // 500000
    int NG16 = (N + 15) / 16;                 // 31250
    char* ws = (char*)d_ws;
    _Float16* qpk  = (_Float16*)ws;                             // 196608 B
    float* simout  = (float*)(ws + 196608);                     // NG16*16*64*4 = 128 MB
    size_t simBytes = (size_t)NG16 * 16 * NQ * sizeof(float);
    float2* candA  = (float2*)(ws + 196608 + simBytes);         // 64*4096*16*8 = 33.5 MB
    size_t candABytes = (size_t)NQ * NMW * 16 * sizeof(float2);
    float2* cand2  = (float2*)(ws + 196608 + simBytes + candABytes);  // 64 KB
    float* out = (float*)d_out;

    prep_kernel<<<NQ, 256, 0, stream>>>(query, qpk);
    sim_kernel<<<GRID, TPB, 0, stream>>>(corpus, qpk, simout, N, NG16);
    mergeA_kernel<<<NMW / 4, 256, 0, stream>>>(simout, candA, N);
    merge1_kernel<<<NQ * NS, 256, 0, stream>>>(candA, cand2, NMW);
    merge2_kernel<<<NQ, 64, 0, stream>>>(cand2, out);
}

// Round 8
// 585.134 us; speedup vs baseline: 2.6724x; 1.5502x over previous
//
#include <hip/hip_runtime.h>
#include <hip/hip_bf16.h>

#define D 768
#define NQ 64
#define KSTEPS 24            // 768 / 32
#define SIMB 256             // sim grid (1 block/CU)
#define SIMT 1024            // sim block threads (16 waves)
#define NSIMW (SIMB * 16)    // 4096 sim waves
#define NMW 4096             // mergeA lists per query
#define NS 8                 // merge1 segments per query
#define CANDCAP 192
#define MARGIN 1e-3f
#define QLDS_BYTES 98304     // 24*4*64*8 halves * 2B

typedef float    f32x4 __attribute__((ext_vector_type(4)));
typedef _Float16 h16x8 __attribute__((ext_vector_type(8)));

typedef const void __attribute__((address_space(1)))* gas_ptr;
typedef void __attribute__((address_space(3)))* las_ptr;

// ---------- float top-k helpers ----------
__device__ __forceinline__ bool kbetter(float v1, int i1, float v2, int i2) {
    return (v1 > v2) || (v1 == v2 && i1 < i2);
}

__device__ __forceinline__ void topk_insert(float (&tv)[16], int (&ti)[16], float v, int idx) {
    if (!kbetter(v, idx, tv[15], ti[15])) return;
    tv[15] = v; ti[15] = idx;
    #pragma unroll
    for (int s = 15; s >= 1; --s) {
        bool sw = kbetter(tv[s], ti[s], tv[s-1], ti[s-1]);
        float av = sw ? tv[s] : tv[s-1];
        float bv = sw ? tv[s-1] : tv[s];
        int   ai = sw ? ti[s] : ti[s-1];
        int   bi = sw ? ti[s-1] : ti[s];
        tv[s-1] = av; tv[s] = bv; ti[s-1] = ai; ti[s] = bi;
    }
}

__device__ __forceinline__ void bitonic16(float (&v)[16], int (&ix)[16]) {
    #pragma unroll
    for (int d = 8; d >= 1; d >>= 1) {
        #pragma unroll
        for (int i = 0; i < 16; ++i) {
            if ((i & d) == 0) {
                int j = i | d;
                bool sw = kbetter(v[j], ix[j], v[i], ix[i]);
                float av = sw ? v[j] : v[i];
                float bv = sw ? v[i] : v[j];
                int   ai = sw ? ix[j] : ix[i];
                int   bi = sw ? ix[i] : ix[j];
                v[i] = av; v[j] = bv; ix[i] = ai; ix[j] = bi;
            }
        }
    }
}

__device__ __forceinline__ void lane_merge(float (&v)[16], int (&ix)[16], int mask) {
    float pv[16]; int pix[16];
    #pragma unroll
    for (int i = 0; i < 16; ++i) {
        pv[i]  = __shfl_xor(v[15 - i], mask);
        pix[i] = __shfl_xor(ix[15 - i], mask);
    }
    #pragma unroll
    for (int i = 0; i < 16; ++i) {
        if (kbetter(pv[i], pix[i], v[i], ix[i])) { v[i] = pv[i]; ix[i] = pix[i]; }
    }
    bitonic16(v, ix);
}

__device__ __forceinline__ void sort64(float& v, int& ix, int l) {
    #pragma unroll
    for (int k = 2; k <= 64; k <<= 1) {
        #pragma unroll
        for (int j = k >> 1; j >= 1; j >>= 1) {
            float ov = __shfl_xor(v, j);
            int   oi = __shfl_xor(ix, j);
            bool dirDesc = ((l & k) == 0);
            bool lower   = ((l & j) == 0);
            bool takeBetter = (lower == dirDesc);
            bool ob = kbetter(ov, oi, v, ix);
            if (takeBetter == ob) { v = ov; ix = oi; }
        }
    }
}

// ---------- double top-k helpers (exact pass) ----------
__device__ __forceinline__ bool kbetterD(double v1, int i1, double v2, int i2) {
    return (v1 > v2) || (v1 == v2 && i1 < i2);
}

__device__ __forceinline__ void topk_insertD(double (&tv)[16], int (&ti)[16], double v, int idx) {
    if (!kbetterD(v, idx, tv[15], ti[15])) return;
    tv[15] = v; ti[15] = idx;
    #pragma unroll
    for (int s = 15; s >= 1; --s) {
        bool sw = kbetterD(tv[s], ti[s], tv[s-1], ti[s-1]);
        double av = sw ? tv[s] : tv[s-1];
        double bv = sw ? tv[s-1] : tv[s];
        int    ai = sw ? ti[s] : ti[s-1];
        int    bi = sw ? ti[s-1] : ti[s];
        tv[s-1] = av; tv[s] = bv; ti[s-1] = ai; ti[s] = bi;
    }
}

__device__ __forceinline__ void bitonic16D(double (&v)[16], int (&ix)[16]) {
    #pragma unroll
    for (int d = 8; d >= 1; d >>= 1) {
        #pragma unroll
        for (int i = 0; i < 16; ++i) {
            if ((i & d) == 0) {
                int j = i | d;
                bool sw = kbetterD(v[j], ix[j], v[i], ix[i]);
                double av = sw ? v[j] : v[i];
                double bv = sw ? v[i] : v[j];
                int    ai = sw ? ix[j] : ix[i];
                int    bi = sw ? ix[i] : ix[j];
                v[i] = av; v[j] = bv; ix[i] = ai; ix[j] = bi;
            }
        }
    }
}

__device__ __forceinline__ void lane_mergeD(double (&v)[16], int (&ix)[16], int mask) {
    double pv[16]; int pix[16];
    #pragma unroll
    for (int i = 0; i < 16; ++i) {
        pv[i]  = __shfl_xor(v[15 - i], mask);
        pix[i] = __shfl_xor(ix[15 - i], mask);
    }
    #pragma unroll
    for (int i = 0; i < 16; ++i) {
        if (kbetterD(pv[i], pix[i], v[i], ix[i])) { v[i] = pv[i]; ix[i] = pix[i]; }
    }
    bitonic16D(v, ix);
}

// ---------- kernel 0: normalize Q; emit fp16-hi fragment pack + fp32 rows ----------
// qpk layout: [ks(24)][qf(4)][lane(64)][8 halves] (hi only, 16 B/lane-fragment)
__global__ __launch_bounds__(256)
void prep_kernel(const float* __restrict__ query, _Float16* __restrict__ qpk,
                 float* __restrict__ qn) {
    int b = blockIdx.x, t = threadIdx.x;
    const float* row = query + b * D;
    float vals[3]; float s = 0.f;
    #pragma unroll
    for (int j = 0; j < 3; ++j) { vals[j] = row[t + 256 * j]; s += vals[j] * vals[j]; }
    #pragma unroll
    for (int m = 1; m < 64; m <<= 1) s += __shfl_xor(s, m);
    __shared__ float ws4[4];
    if ((t & 63) == 0) ws4[t >> 6] = s;
    __syncthreads();
    float qnorm = sqrtf(ws4[0] + ws4[1] + ws4[2] + ws4[3]);
    int qf = b >> 4;
    #pragma unroll
    for (int j = 0; j < 3; ++j) {
        int col = t + 256 * j;
        float vn = vals[j] / qnorm;
        qn[b * D + col] = vn;
        int ks = col >> 5, unit = (col >> 3) & 3, sub = col & 7;
        int lane = (b & 15) + unit * 16;
        qpk[(((size_t)ks * 4 + qf) * 64 + lane) * 8 + sub] = (_Float16)vn;
    }
}

// ---------- kernel 1: pass-1 sims — Q in LDS, barrier-free corpus stream ----------
__global__ __launch_bounds__(SIMT, 4)
void sim_kernel(const float* __restrict__ corpus,
                const _Float16* __restrict__ qpk,
                float* __restrict__ simout, int N, int NG16) {
    extern __shared__ __align__(16) char smem[];   // 96 KB Q pack
    int t = threadIdx.x, w = t >> 6, l = t & 63;
    int n16 = l & 15, kg = l >> 4;

    // stage Q pack into LDS once (linear dest, 16B DMA)
    #pragma unroll
    for (int j = 0; j < 6; ++j) {
        int idx = t + SIMT * j;                  // 6144 granules of 16 B
        const _Float16* src = qpk + (size_t)idx * 8;
        char* dst = smem + (size_t)idx * 16;
        __builtin_amdgcn_global_load_lds((gas_ptr)(const void*)src, (las_ptr)(void*)dst, 16, 0, 0);
    }
    __syncthreads();
    const _Float16* qlds = (const _Float16*)smem;

    for (int g = blockIdx.x * 16 + w; g < NG16; g += NSIMW) {
        int n = g * 16 + n16;
        int nc = n < N ? n : N - 1;
        const float* pc = corpus + (size_t)nc * D + kg * 8;

        f32x4 acc[4];
        #pragma unroll
        for (int qf = 0; qf < 4; ++qf) acc[qf] = (f32x4)(0.f);
        float ps = 0.f;

        #pragma unroll 4
        for (int ks = 0; ks < KSTEPS; ++ks) {
            f32x4 c0 = *(const f32x4*)(pc + ks * 32);
            f32x4 c1 = *(const f32x4*)(pc + ks * 32 + 4);
            h16x8 hi;
            #pragma unroll
            for (int i = 0; i < 4; ++i) {
                hi[i]     = (_Float16)c0[i];
                hi[4 + i] = (_Float16)c1[i];
                ps += c0[i] * c0[i] + c1[i] * c1[i];
            }
            #pragma unroll
            for (int qf = 0; qf < 4; ++qf) {
                h16x8 qh = *(const h16x8*)(qlds + (((size_t)ks * 4 + qf) * 64 + l) * 8);
                acc[qf] = __builtin_amdgcn_mfma_f32_16x16x32_f16(qh, hi, acc[qf], 0, 0, 0);
            }
        }

        // corpus row norm: lanes {l, l^16, l^32, l^48} hold k-slices of row n16
        ps += __shfl_xor(ps, 16);
        ps += __shfl_xor(ps, 32);
        float inv = 1.0f / sqrtf(ps);

        if (n < N) {
            float* so = simout + ((size_t)g * 16 + n16) * NQ + kg * 4;
            #pragma unroll
            for (int qf = 0; qf < 4; ++qf) {
                f32x4 v = acc[qf] * inv;
                *(f32x4*)(so + qf * 16) = v;
            }
        }
    }
}

// ---------- kernel 2: stream sims -> per-wave per-query top-16 ----------
__global__ __launch_bounds__(256)
void mergeA_kernel(const float* __restrict__ simout, float2* __restrict__ candA, int N) {
    int t = threadIdx.x, w = t >> 6, l = t & 63;
    int ww = blockIdx.x * 4 + w;
    int chunk = (N + NMW - 1) / NMW;
    int n0 = ww * chunk, n1 = min(N, n0 + chunk);

    float tv[16]; int ti[16];
    #pragma unroll
    for (int s = 0; s < 16; ++s) { tv[s] = -INFINITY; ti[s] = 0x7fffffff; }

    int n = n0;
    for (; n + 8 <= n1; n += 8) {
        float v[8];
        #pragma unroll
        for (int j = 0; j < 8; ++j) v[j] = simout[(size_t)(n + j) * NQ + l];
        #pragma unroll
        for (int j = 0; j < 8; ++j) topk_insert(tv, ti, v[j], n + j);
    }
    for (; n < n1; ++n) topk_insert(tv, ti, simout[(size_t)n * NQ + l], n);

    float2* dst = candA + ((size_t)l * NMW + ww) * 16;
    #pragma unroll
    for (int s = 0; s < 16; ++s) dst[s] = make_float2(tv[s], __int_as_float(ti[s]));
}

// ---------- kernel 3: partial merge — 8 segments per query ----------
__global__ __launch_bounds__(256)
void merge1_kernel(const float2* __restrict__ cand, float2* __restrict__ cand2, int NWV) {
    int q = blockIdx.x >> 3, seg = blockIdx.x & (NS - 1);
    int t = threadIdx.x, w = t >> 6, l = t & 63;
    int total = NWV * 16;
    int chunk = (total + NS - 1) / NS;
    int e0 = seg * chunk, e1 = min(total, e0 + chunk);
    const float2* src = cand + (size_t)q * total;
    float tv[16]; int ti[16];
    #pragma unroll
    for (int s = 0; s < 16; ++s) { tv[s] = -INFINITY; ti[s] = 0x7fffffff; }
    for (int e = e0 + t; e < e1; e += 256) {
        float2 ce = src[e];
        topk_insert(tv, ti, ce.x, __float_as_int(ce.y));
    }
    lane_merge(tv, ti, 1);  lane_merge(tv, ti, 2);  lane_merge(tv, ti, 4);
    lane_merge(tv, ti, 8);  lane_merge(tv, ti, 16); lane_merge(tv, ti, 32);
    __shared__ float2 stage[64];
    if (l == 0) {
        #pragma unroll
        for (int s = 0; s < 16; ++s) stage[w * 16 + s] = make_float2(tv[s], __int_as_float(ti[s]));
    }
    __syncthreads();
    if (t < 64) {
        float2 ce = stage[t];
        float v = ce.x; int ix = __float_as_int(ce.y);
        sort64(v, ix, t);
        if (t < 16) cand2[((size_t)q * NS + seg) * 16 + t] = make_float2(v, __int_as_float(ix));
    }
}

// ---------- kernel 4: approx top-16 -> per-query threshold; zero counters ----------
__global__ __launch_bounds__(64)
void merge2t_kernel(const float2* __restrict__ cand2, float* __restrict__ thr,
                    int* __restrict__ cnt) {
    int q = blockIdx.x, l = threadIdx.x;
    const float2* src = cand2 + (size_t)q * (NS * 16);
    float2 a = src[l], b = src[l + 64];
    float v1 = a.x; int i1 = __float_as_int(a.y);
    float v2 = b.x; int i2 = __float_as_int(b.y);
    sort64(v1, i1, l);
    sort64(v2, i2, l);
    float sv = __shfl(v2, (l - 16) & 63);
    int   si = __shfl(i2, (l - 16) & 63);
    float mv = (l < 16) ? v1 : ((l < 32) ? sv : -INFINITY);
    int   mi = (l < 16) ? i1 : ((l < 32) ? si : 0x7fffffff);
    sort64(mv, mi, l);
    if (l == 15) {           // mv = approx v16
        thr[q] = mv - MARGIN;
        cnt[q] = 0;
    }
}

// ---------- kernel 5: filter — collect candidates above threshold ----------
__global__ __launch_bounds__(256)
void filter_kernel(const float* __restrict__ simout, const float* __restrict__ thr,
                   int* __restrict__ cnt, int* __restrict__ candx, int N) {
    int t = threadIdx.x, w = t >> 6, l = t & 63;
    int wid = blockIdx.x * 4 + w;
    int nwaves = gridDim.x * 4;
    float th = thr[l];
    for (int n = wid; n < N; n += nwaves) {
        float v = simout[(size_t)n * NQ + l];
        if (v >= th) {
            int s = atomicAdd(&cnt[l], 1);
            if (s < CANDCAP) candx[l * CANDCAP + s] = n;
        }
    }
}

// ---------- kernel 6: exact fp64 re-rank of candidates ----------
__global__ __launch_bounds__(256)
void exact_kernel(const float* __restrict__ corpus, const float* __restrict__ qn,
                  const int* __restrict__ cnt, const int* __restrict__ candx,
                  float* __restrict__ out, int N) {
    int q = blockIdx.x, t = threadIdx.x, w = t >> 6, l = t & 63;
    int m = min(cnt[q], CANDCAP);
    __shared__ double vals[CANDCAP];
    __shared__ int    idxs[CANDCAP];

    const float* qr = qn + q * D;
    for (int c = w; c < m; c += 4) {
        int n = candx[q * CANDCAP + c];
        const float* cr = corpus + (size_t)n * D;
        double acc = 0.0, cs = 0.0;
        #pragma unroll
        for (int j = 0; j < D / 64; ++j) {
            double cv = (double)cr[l + j * 64];
            acc += (double)qr[l + j * 64] * cv;
            cs  += cv * cv;
        }
        #pragma unroll
        for (int msk = 1; msk < 64; msk <<= 1) {
            acc += __shfl_xor(acc, msk);
            cs  += __shfl_xor(cs, msk);
        }
        if (l == 0) { vals[c] = acc / sqrt(cs); idxs[c] = n; }
    }
    __syncthreads();

    if (w == 0) {
        double tv[16]; int ti[16];
        #pragma unroll
        for (int s = 0; s < 16; ++s) { tv[s] = -1e300; ti[s] = 0x7fffffff; }
        for (int r = 0; r < CANDCAP / 64; ++r) {
            int e = l + r * 64;
            if (e < m) topk_insertD(tv, ti, vals[e], idxs[e]);
        }
        lane_mergeD(tv, ti, 1);  lane_mergeD(tv, ti, 2);  lane_mergeD(tv, ti, 4);
        lane_mergeD(tv, ti, 8);  lane_mergeD(tv, ti, 16); lane_mergeD(tv, ti, 32);
        if (l == 0) {
            #pragma unroll
            for (int s = 0; s < 16; ++s) {
                out[q * 16 + s]           = (float)tv[s];
                out[NQ * 16 + q * 16 + s] = (float)ti[s];
            }
        }
    }
}

extern "C" void kernel_launch(void* const* d_in, const int* in_sizes, int n_in,
                              void* d_out, int out_size, void* d_ws, size_t ws_size,
                              hipStream_t stream) {
    const float* query  = (const float*)d_in[0];
    const float* corpus = (const float*)d_in[1];
    int N    = in_sizes[1] / D;               // 500000
    int NG16 = (N + 15) / 16;                 // 31250

    char* ws = (char*)d_ws;
    _Float16* qpk = (_Float16*)ws;                              // 98304 B
    float* qn     = (float*)(ws + 98304);                       // 196608 B
    float* simout = (float*)(ws + 98304 + 196608);              // NG16*16*64*4 = 128 MB
    size_t simBytes = (size_t)NG16 * 16 * NQ * sizeof(float);
    char* p = ws + 98304 + 196608 + simBytes;
    float2* candA = (float2*)p;                                 // 64*4096*16*8 = 33.5 MB
    size_t candABytes = (size_t)NQ * NMW * 16 * sizeof(float2);
    float2* cand2 = (float2*)(p + candABytes);                  // 64 KB
    float*  thr   = (float*)(p + candABytes + 65536);           // 256 B
    int*    cnt   = (int*)(p + candABytes + 65536 + 256);       // 256 B
    int*    candx = (int*)(p + candABytes + 65536 + 512);       // 64*192*4 = 48 KB
    float* out = (float*)d_out;

    (void)hipFuncSetAttribute((const void*)sim_kernel,
                              hipFuncAttributeMaxDynamicSharedMemorySize, QLDS_BYTES);

    prep_kernel<<<NQ, 256, 0, stream>>>(query, qpk, qn);
    sim_kernel<<<SIMB, SIMT, QLDS_BYTES, stream>>>(corpus, qpk, simout, N, NG16);
    mergeA_kernel<<<NMW / 4, 256, 0, stream>>>(simout, candA, N);
    merge1_kernel<<<NQ * NS, 256, 0, stream>>>(candA, cand2, NMW);
    merge2t_kernel<<<NQ, 64, 0, stream>>>(cand2, thr, cnt);
    filter_kernel<<<1024, 256, 0, stream>>>(simout, thr, cnt, candx, N);
    exact_kernel<<<NQ, 256, 0, stream>>>(corpus, qn, cnt, candx, out, N);
}